// Round 13
// baseline (277.167 us; speedup 1.0000x reference)
//
#include <hip/hip_runtime.h>

// HausdorffDTLoss: exact separable EDT (fg & bg) per image, then
// mean((pred-target)^2 * (pred_dt^2 + target_dt^2)).
// Envelope identity: g[i] = min_j f[j]+(i-j)^2 = i^2 + min_j (h[j]-2ij),
// h[j]=f[j]+j^2, candidates advanced by additive chains (exact: all values
// are integers < 2^17; fp32 math exact -- R1-R12: absmax 0.0).
//
// R13 vs R12 (270us; (512,8) spilled old xloss catastrophically; zy occupancy
// 54% without speedup -> stall is barrier-phase lock-step of few big blocks):
//  - zy: 256-thr blocks, 2048 of them (z-half split for the envelope; full
//    bitmask build per block). 18.9KB LDS -> 8 blocks/CU, 32 waves/CU, halved
//    phases. Same-slab siblings at blockIdx strides 256/512 -> same XCD (L2).
//    (256,8): VGPR<=64, acc[16] shape fits (R4 measured 40).
//  - xloss: env-A output parked in u16 LDS buffer, hx reused for B -> live
//    set ~30 floats, (512,8) fits -> 32 waves/CU without the R12 spill.

constexpr int BIGI = 49153;      // 3*128^2+1, matches reference BIG exactly
constexpr int NVOX = 4194304;    // voxels per tensor (2 samples x 128^3)
constexpr int ST   = 65;         // dword row stride: (65q+c)%32=(q+c)%32 -> 2-way (free)

__global__ void zero_kernel(float* out, int* flags) {
    out[0] = 0.0f;
    flags[0] = 0; flags[1] = 0; flags[2] = 0; flags[3] = 0;
}

// Fused binarize + bitmask z-EDT + y-envelope for one (b,x) slab, one image,
// one polarity, one z-half. 256 thr, 18.9KB LDS, 8 blocks/CU.
__global__ __launch_bounds__(256, 8) void zy_kernel(const float* __restrict__ pred,
                                                    const float* __restrict__ tgt,
                                                    unsigned short* __restrict__ ws,
                                                    int* __restrict__ flags) {
    __shared__ unsigned int hz[ST * ST];           // packed u16 pairs: (y-pair, zz)
    __shared__ unsigned long long bm[256];         // site bitmasks: [y][z-half]
    const int t   = blockIdx.x;
    const int s   = t & 255;                       // slab id: b(2) x x(128)
    const int g   = t >> 8;                        // 0..7
    const int img = g & 1;
    const int pol = (g >> 1) & 1;                  // 0: fg EDT (sites=~fg), 1: bg
    const int zh  = g >> 2;                        // z-half this block owns
    const int b   = s >> 7;
    const int x   = s & 127;
    const int sb  = (b * 128 + x) * 16384;         // + y*128 + z
    const int tid = threadIdx.x;
    const float* im = img ? tgt : pred;

    // ---- stage: full slab read -> per-wave ballot -> site bitmasks ----
    bool anyfg = false;
#pragma unroll
    for (int k = 0; k < 64; ++k) {
        int l = tid + k * 256;
        float v = im[sb + l];
        bool fg = v > 0.5f;
        anyfg |= fg;
        bool site = pol ? fg : !fg;
        unsigned long long bal = __ballot(site);
        if ((tid & 63) == 0) bm[l >> 6] = bal;     // l>>6 uniform per wave
    }
    if (!pol && !zh && __ballot(anyfg) != 0ULL && (tid & 63) == 0)
        atomicOr(flags + img * 2 + b, 1);
    __syncthreads();

    // ---- bitmask z-EDT for this block's 64 z-columns (zh: block-uniform) ----
    unsigned short* hu = (unsigned short*)hz;
    const int zz = tid & 63;
    const int z  = zh * 64 + zz;
#pragma unroll
    for (int k = 0; k < 32; ++k) {
        int y = (tid >> 6) + k * 4;
        unsigned long long m0 = bm[2 * y], m1 = bm[2 * y + 1];
        int d;
        if (z < 64) {
            unsigned long long lm = m0 << (63 - z);
            unsigned long long rm = m0 >> z;
            int dfwd = lm ? __builtin_clzll(lm) : 999;
            int db0  = rm ? __builtin_ctzll(rm) : 999;
            int db1  = (m1 ? __builtin_ctzll(m1) : 999) + (64 - z);
            d = min(dfwd, min(db0, db1));
        } else {
            int za = z - 64;
            unsigned long long lm = m1 << (63 - za);
            unsigned long long rm = m1 >> za;
            int df1 = lm ? __builtin_clzll(lm) : 999;
            int df0 = (m0 ? __builtin_clzll(m0) : 999) + za + 1;
            int dbw = rm ? __builtin_ctzll(rm) : 999;
            d = min(min(df1, df0), dbw);
        }
        int f = (d <= 127) ? d * d : BIGI;         // empty line -> BIG (exact)
        hu[((y >> 1) * ST + zz) * 2 + (y & 1)] = (unsigned short)(f + y * y);
    }
    __syncthreads();

    // ---- y-envelope: c = zz column, 4 groups, two SEQUENTIAL i-rounds ----
    unsigned short* outv = ws + (size_t)(img * 2 + pol) * NVOX + sb + zh * 64;
    const int c = tid & 63;
#pragma clang loop unroll(disable)
    for (int r = 0; r < 2; ++r) {                  // one acc[16] set live at a time
        const int i0 = (tid >> 6) * 16 + r * 64;
        const float i0f = (float)i0;
        float acc[16];
#pragma unroll
        for (int k = 0; k < 16; ++k) acc[k] = 3.0e38f;
        const unsigned int* p = hz + c;
        unsigned int vc = p[0];
        float jm2 = 0.0f;                          // -2*(2q)
        for (int q = 0; q < 64; ++q) {
            unsigned int vn = p[(q + 1) * ST];     // 1-pair prefetch (row 64 slack)
            float h0 = (float)(vc & 0xffffu);      // y = 2q
            float h1 = (float)(vc >> 16);          // y = 2q+1
            float jb = jm2 - 2.0f;
            float c0 = fmaf(jm2, i0f, h0);         // candidate at i = i0
            float c1 = fmaf(jb,  i0f, h1);
#pragma unroll
            for (int k = 0; k < 16; ++k) {         // additive chain: no literals
                acc[k] = fminf(acc[k], fminf(c0, c1));
                c0 += jm2; c1 += jb;
            }
            jm2 -= 4.0f;
            vc = vn;
        }
#pragma unroll
        for (int k = 0; k < 16; ++k) {             // gy = acc + y^2 <= 49153: u16
            float iif = i0f + (float)k;
            outv[(i0 + k) * 128 + c] = (unsigned short)(unsigned int)fmaf(iif, iif, acc[k]);
        }
    }
}

// X-envelope for A and B + fused loss. env-A result parked in u16 LDS, hx
// reused for B -> max ~30 live floats. 512 thr, 33.3KB LDS, 4 blocks/CU.
__global__ __launch_bounds__(512, 8) void xloss_kernel(const float* __restrict__ pred,
                                                       const float* __restrict__ tgt,
                                                       const unsigned short* __restrict__ ws,
                                                       const int* __restrict__ flags,
                                                       float* __restrict__ out) {
    __shared__ unsigned int hx[ST * ST];
    __shared__ unsigned short gbuf[128 * 64];      // gA per (x, c), u16 exact
    __shared__ float red[8];
    const int t    = blockIdx.x;
    const int img  = t & 1;                    // adjacent blocks share pred/tgt chunk
    const int b    = (t >> 1) & 1;
    const int q0   = (t >> 2) * 64;
    const int base = b * 2097152 + q0;         // + x*16384 + c
    const int tid  = threadIdx.x;
    const int c    = tid & 63;
    const int i0   = (tid >> 6) * 16;          // 8 groups x 16 = all 128 x
    const float i0f = (float)i0;
    unsigned short* hu = (unsigned short*)hx;
    const unsigned short* A16 = ws + (size_t)(img * 2) * NVOX;
    const unsigned short* B16 = A16 + NVOX;
    float acc[16];

    // ---- stage A ----
#pragma unroll
    for (int k = 0; k < 16; ++k) {
        int l = tid + k * 512;
        int cc = l & 63, j = l >> 6;
        unsigned int v = A16[base + j * 16384 + cc];
        hu[((j >> 1) * ST + cc) * 2 + (j & 1)] = (unsigned short)(v + j * j); // <=65282
    }
    __syncthreads();

    // ---- envelope A -> park gA in gbuf ----
    {
#pragma unroll
        for (int k = 0; k < 16; ++k) acc[k] = 3.0e38f;
        const unsigned int* p = hx + c;
        unsigned int vc = p[0];
        float jm2 = 0.0f;
        for (int q = 0; q < 64; ++q) {
            unsigned int vn = p[(q + 1) * ST];
            float h0 = (float)(vc & 0xffffu);
            float h1 = (float)(vc >> 16);
            float jb = jm2 - 2.0f;
            float c0 = fmaf(jm2, i0f, h0);
            float c1 = fmaf(jb,  i0f, h1);
#pragma unroll
            for (int k = 0; k < 16; ++k) {
                acc[k] = fminf(acc[k], fminf(c0, c1));
                c0 += jm2; c1 += jb;
            }
            jm2 -= 4.0f;
            vc = vn;
        }
#pragma unroll
        for (int k = 0; k < 16; ++k) {
            float iif = i0f + (float)k;
            gbuf[(i0 + k) * 64 + c] =
                (unsigned short)(unsigned int)fmaf(iif, iif, acc[k]); // gA <= 49153
        }
    }
    __syncthreads();                               // hx fully read -> safe to reuse

    // ---- stage B into hx ----
#pragma unroll
    for (int k = 0; k < 16; ++k) {
        int l = tid + k * 512;
        int cc = l & 63, j = l >> 6;
        unsigned int v = B16[base + j * 16384 + cc];
        hu[((j >> 1) * ST + cc) * 2 + (j & 1)] = (unsigned short)(v + j * j);
    }
    __syncthreads();

    // ---- envelope B + fused loss ----
    float s = 0.0f;
    {
#pragma unroll
        for (int k = 0; k < 16; ++k) acc[k] = 3.0e38f;
        const unsigned int* p = hx + c;
        unsigned int vc = p[0];
        float jm2 = 0.0f;
        for (int q = 0; q < 64; ++q) {
            unsigned int vn = p[(q + 1) * ST];
            float h0 = (float)(vc & 0xffffu);
            float h1 = (float)(vc >> 16);
            float jb = jm2 - 2.0f;
            float c0 = fmaf(jm2, i0f, h0);
            float c1 = fmaf(jb,  i0f, h1);
#pragma unroll
            for (int k = 0; k < 16; ++k) {
                acc[k] = fminf(acc[k], fminf(c0, c1));
                c0 += jm2; c1 += jb;
            }
            jm2 -= 4.0f;
            vc = vn;
        }
#pragma unroll
        for (int k = 0; k < 16; ++k) {
            float iif = i0f + (float)k;
            float gB = fmaf(iif, iif, acc[k]);
            float gA = (float)gbuf[(i0 + k) * 64 + c];
            int v = base + (i0 + k) * 16384 + c;   // coalesced across c per k
            float d = pred[v] - tgt[v];
            float fld = sqrtf(gA) + sqrtf(gB);
            s += d * d * fld * fld;
        }
    }
    if (!flags[img * 2 + b]) s = 0.0f;
#pragma unroll
    for (int off = 32; off > 0; off >>= 1) s += __shfl_down(s, off);
    if ((tid & 63) == 0) red[tid >> 6] = s;
    __syncthreads();
    if (tid == 0) {
        float tot = 0.0f;
#pragma unroll
        for (int w = 0; w < 8; ++w) tot += red[w];
        atomicAdd(out, tot * (1.0f / 4194304.0f));
    }
}

extern "C" void kernel_launch(void* const* d_in, const int* in_sizes, int n_in,
                              void* d_out, int out_size, void* d_ws, size_t ws_size,
                              hipStream_t stream) {
    const float* pred = (const float*)d_in[0];
    const float* tgt  = (const float*)d_in[1];
    float* out = (float*)d_out;
    unsigned short* ws16 = (unsigned short*)d_ws;  // 4 u16 volumes = 33.6 MB
    int* flags = (int*)(ws16 + 4 * (size_t)NVOX);  // [img0_b0, img0_b1, img1_b0, img1_b1]

    zero_kernel<<<1, 1, 0, stream>>>(out, flags);
    zy_kernel<<<dim3(2048), 256, 0, stream>>>(pred, tgt, ws16, flags);
    xloss_kernel<<<dim3(1024), 512, 0, stream>>>(pred, tgt, ws16, flags, out);
}